// Round 2
// baseline (1672.109 us; speedup 1.0000x reference)
//
#include <hip/hip_runtime.h>

typedef unsigned short u16;
typedef unsigned int   u32;
typedef __attribute__((ext_vector_type(8))) short short8;
typedef __attribute__((ext_vector_type(4))) float f32x4;

#define IMG_BYTES  557568      /* 66*66*64*2 (padded bf16 image) */
#define WS_SCALE   0
#define WS_SHIFT   256
#define WS_PART    512         /* 16 groups * 128 floats = 8192 B */
#define WS_WA      8704        /* 3 * 110592 u16 = 663552 B */
#define WS_BNXP    672256      /* 64 * IMG_BYTES */
#define WS_HC      (WS_BNXP + 64*IMG_BYTES)          /* 4 buffers x 4*IMG_BYTES */
#define WS_CSTATE  (WS_HC + 16*IMG_BYTES)            /* 4*64*4096 f32 = 4 MiB */

__device__ __forceinline__ u16 f2b(float f){
  u32 x = __float_as_uint(f);
  return (u16)((x + 0x7fffu + ((x>>16)&1u)) >> 16);
}
__device__ __forceinline__ float sigm(float x){ return 1.f/(1.f+__expf(-x)); }
__device__ __forceinline__ float tanh_(float x){
  float e = __expf(2.f*fabsf(x));
  float t = 1.f - 2.f/(e+1.f);      /* inf-safe -> 1 */
  return copysignf(t, x);
}

/* ---- weight transform: f32 [O][C][3][3] -> bf16 wA[j][o][tap*64+c] ---- */
__global__ void k_wt(const float* __restrict__ c1, const float* __restrict__ c2h,
                     const float* __restrict__ h2h, u16* __restrict__ wA){
  int idx = blockIdx.x*256 + threadIdx.x;
  if (idx >= 3*110592) return;
  int jj = idx / 110592, rem = idx % 110592;
  int o = rem / 576, k = rem % 576;
  int tap = k >> 6, c = k & 63;
  const float* src = (jj==0) ? c1 : ((jj==1) ? c2h : h2h);
  wA[idx] = f2b(src[(o*64 + c)*9 + tap]);
}

/* ---- BN partial sums: block (c, g) reduces imgs g*4..g*4+3 (f32 input) ---- */
__global__ void k_bnsum(const float* __restrict__ x, float* __restrict__ part){
  int c = blockIdx.x & 63, g = blockIdx.x >> 6;
  int tid = threadIdx.x, w = tid >> 6, lane = tid & 63;
  float s = 0.f, s2 = 0.f;
  for (int im = 0; im < 4; ++im){
    const float* base = x + (((size_t)((g*4+im)*64 + c)) << 12);
    #pragma unroll
    for (int it = 0; it < 4; ++it){
      float4 v = *(const float4*)(base + (((it<<8) + tid) << 2));
      s  += v.x + v.y + v.z + v.w;
      s2 += v.x*v.x + v.y*v.y + v.z*v.z + v.w*v.w;
    }
  }
  #pragma unroll
  for (int off = 32; off > 0; off >>= 1){
    s  += __shfl_down(s,  off);
    s2 += __shfl_down(s2, off);
  }
  __shared__ float red[8];
  if (lane == 0){ red[w] = s; red[4+w] = s2; }
  __syncthreads();
  if (tid == 0){
    float S  = red[0]+red[1]+red[2]+red[3];
    float S2 = red[4]+red[5]+red[6]+red[7];
    part[(g<<7) + c] = S;
    part[(g<<7) + 64 + c] = S2;
  }
}

/* ---- BN finalize: scale/shift per channel (f32 gamma/beta) ---- */
__global__ void k_bnfin(const float* __restrict__ part, const float* __restrict__ gamma,
                        const float* __restrict__ beta, float* __restrict__ scale,
                        float* __restrict__ shift){
  int c = threadIdx.x;
  float S = 0.f, S2 = 0.f;
  for (int g = 0; g < 16; ++g){ S += part[(g<<7)+c]; S2 += part[(g<<7)+64+c]; }
  const float inv = 1.f/262144.f;
  float mean = S*inv;
  float var  = S2*inv - mean*mean;
  float sc = gamma[c] * rsqrtf(var + 1e-5f);
  scale[c] = sc;
  shift[c] = beta[c] - mean*sc;
}

/* ---- BN apply + transpose f32 NCHW -> padded bf16 [img][66][66][64] ---- */
__global__ void k_bnx(const float* __restrict__ x, const float* __restrict__ scale,
                      const float* __restrict__ shift, char* __restrict__ bnxp){
  int img = blockIdx.x >> 6, r = blockIdx.x & 63;
  int col = threadIdx.x & 63, cq = threadIdx.x >> 6;
  const float* xb = x + (((size_t)(img*64 + cq*16)) << 12) + (r<<6) + col;
  union { u16 u[16]; uint4 v[2]; } pk;
  #pragma unroll
  for (int i = 0; i < 16; ++i){
    int c = cq*16 + i;
    float vv = xb[((size_t)i) << 12];
    pk.u[i] = f2b(vv*scale[c] + shift[c]);
  }
  char* dst = bnxp + (size_t)img*IMG_BYTES + ((size_t)((r+1)*66 + col + 1) << 7) + cq*32;
  *(uint4*)dst = pk.v[0];
  *(uint4*)(dst+16) = pk.v[1];
}

/* ---- fused ConvLSTM step: conv1(bnx_t)+c2h(c)+h2h(h)+bias -> gates -> h,c ----
   reads padded bf16 src buffers (t parity), writes dst buffers (t+1 parity). */
__global__ __launch_bounds__(256,2) void k_step(
    const char* __restrict__ bnxp,
    const char* __restrict__ cpad_s, const char* __restrict__ hpad_s,
    char* __restrict__ cpad_d, char* __restrict__ hpad_d,
    const u16* __restrict__ wA, const float* __restrict__ b1,
    float* __restrict__ cstate, float* __restrict__ out, int t)
{
  __shared__ __align__(16) char smem[38016];
  const int tid = threadIdx.x;
  const int w = tid >> 6, lane = tid & 63;
  const int l15 = lane & 15, l4 = lane >> 4;
  const int bid = blockIdx.x;
  const int n = bid >> 5, pt = bid & 31;
  const int r0 = pt << 1;
  const int row_w = w >> 1, colw = (w & 1) << 5;

  const char* gb0 = bnxp + (size_t)(t*4+n)*IMG_BYTES + r0*8448;
  const char* gb1 = cpad_s + (size_t)n*IMG_BYTES + r0*8448;
  const char* gb2 = hpad_s + (size_t)n*IMG_BYTES + r0*8448;

  f32x4 acc[12][2];
  #pragma unroll
  for (int a = 0; a < 12; ++a){
    #pragma unroll
    for (int b = 0; b < 2; ++b)
      acc[a][b] = (f32x4){0.f,0.f,0.f,0.f};
  }

  const int boff_lane = (row_w*66 + colw + l15)*144 + l4*16;
  const int aoff_lane = l15*1152 + l4*16;

  for (int j = 0; j < 3; ++j){
    const char* gbj = (j==0) ? gb0 : ((j==1) ? gb1 : gb2);
    const uint4* g = (const uint4*)gbj;
    for (int i = tid; i < 2112; i += 256)
      *(uint4*)(smem + (i>>3)*144 + ((i&7)<<4)) = g[i];
    __syncthreads();

    const char* wj = (const char*)wA + j*221184;
    for (int kh = 0; kh < 3; ++kh){
      for (int kw = 0; kw < 3; ++kw){
        #pragma unroll
        for (int cc = 0; cc < 2; ++cc){
          const int bo = boff_lane + (kh*66 + kw)*144 + (cc<<6);
          short8 bf0 = *(const short8*)(smem + bo);
          short8 bf1 = *(const short8*)(smem + bo + 2304);
          const char* wp = wj + aoff_lane + (kh*3+kw)*128 + (cc<<6);
          #pragma unroll
          for (int fr = 0; fr < 12; ++fr){
            short8 af = *(const short8*)(wp + fr*18432);
            acc[fr][0] = __builtin_amdgcn_mfma_f32_16x16x32_bf16(af, bf0, acc[fr][0], 0,0,0);
            acc[fr][1] = __builtin_amdgcn_mfma_f32_16x16x32_bf16(af, bf1, acc[fr][1], 0,0,0);
          }
        }
      }
    }
    __syncthreads();
  }

  /* epilogue: gates fully in-register (f=frag 0-3, o=frag 4-7, g=frag 8-11) */
  const int rimg = r0 + row_w;
  u16* sh = (u16*)smem + w*2048;
  u16* sc = (u16*)smem + 8192 + w*2048;
  const size_t cb = ((size_t)(n*64)) << 12;
  const size_t ob = ((size_t)((t*4+n)*64)) << 12;

  #pragma unroll
  for (int fr = 0; fr < 4; ++fr){
    #pragma unroll
    for (int r = 0; r < 4; ++r){
      const int gc = fr*16 + l4*4 + r;
      const float bf_ = b1[gc];
      const float bo_ = b1[64+gc];
      const float bg_ = b1[128+gc];
      #pragma unroll
      for (int cf = 0; cf < 2; ++cf){
        const int idx = (cf<<4) + l15;
        const int p = (rimg<<6) + colw + idx;
        float fv = acc[fr][cf][r]   + bf_;
        float ov = acc[fr+4][cf][r] + bo_;
        float gv = acc[fr+8][cf][r] + bg_;
        float f  = sigm(fv);
        float og = sigm(ov);
        float g  = tanh_(gv);
        float* cp = cstate + cb + (((size_t)gc)<<12) + p;
        float cprev = *cp;
        float cn = f*cprev + (1.f-f)*g;
        float hn = og * tanh_(cn);
        *cp = cn;
        out[ob + (((size_t)gc)<<12) + p] = hn;
        sh[idx*64 + gc] = f2b(hn);
        sc[idx*64 + gc] = f2b(cn);
      }
    }
  }
  __syncthreads();

  /* flush padded bf16 h/c tiles (contiguous 4 KiB per wave) into DST buffers */
  char* hdst = hpad_d + (size_t)n*IMG_BYTES + (size_t)((rimg+1)*66 + colw + 1)*128;
  char* cdst = cpad_d + (size_t)n*IMG_BYTES + (size_t)((rimg+1)*66 + colw + 1)*128;
  const char* shc = (const char*)sh;
  const char* scc = (const char*)sc;
  #pragma unroll
  for (int q = 0; q < 4; ++q){
    *(uint4*)(hdst + q*1024 + lane*16) = *(const uint4*)(shc + q*1024 + lane*16);
    *(uint4*)(cdst + q*1024 + lane*16) = *(const uint4*)(scc + q*1024 + lane*16);
  }
}

extern "C" void kernel_launch(void* const* d_in, const int* in_sizes, int n_in,
                              void* d_out, int out_size, void* d_ws, size_t ws_size,
                              hipStream_t stream)
{
  (void)in_sizes; (void)n_in; (void)out_size; (void)ws_size;
  const float* x     = (const float*)d_in[0];
  const float* gamma = (const float*)d_in[1];
  const float* beta  = (const float*)d_in[2];
  const float* c1w   = (const float*)d_in[3];
  const float* c1b   = (const float*)d_in[4];
  const float* wh2h  = (const float*)d_in[5];
  const float* wc2h  = (const float*)d_in[6];
  char* ws  = (char*)d_ws;
  float* out = (float*)d_out;

  char* hpad0 = ws + WS_HC;
  char* cpad0 = ws + WS_HC + (size_t)4*IMG_BYTES;
  char* hpad1 = ws + WS_HC + (size_t)8*IMG_BYTES;
  char* cpad1 = ws + WS_HC + (size_t)12*IMG_BYTES;

  /* zero padded buffers (halos) + h/c ping-pong + c state; every call (graph-safe) */
  hipMemsetAsync(ws + WS_BNXP, 0, (size_t)64*IMG_BYTES, stream);
  hipMemsetAsync(ws + WS_HC, 0, (size_t)16*IMG_BYTES, stream);
  hipMemsetAsync(ws + WS_CSTATE, 0, (size_t)4*64*4096*4, stream);

  k_wt<<<1296, 256, 0, stream>>>(c1w, wc2h, wh2h, (u16*)(ws + WS_WA));
  k_bnsum<<<1024, 256, 0, stream>>>(x, (float*)(ws + WS_PART));
  k_bnfin<<<1, 64, 0, stream>>>((const float*)(ws + WS_PART), gamma, beta,
                                (float*)(ws + WS_SCALE), (float*)(ws + WS_SHIFT));
  k_bnx<<<4096, 256, 0, stream>>>(x, (const float*)(ws + WS_SCALE),
                                  (const float*)(ws + WS_SHIFT), ws + WS_BNXP);
  for (int t = 0; t < 16; ++t){
    const char* cs = (t & 1) ? cpad1 : cpad0;
    const char* hs = (t & 1) ? hpad1 : hpad0;
    char* cd = (t & 1) ? cpad0 : cpad1;
    char* hd = (t & 1) ? hpad0 : hpad1;
    k_step<<<128, 256, 0, stream>>>(ws + WS_BNXP, cs, hs, cd, hd,
                                    (const u16*)(ws + WS_WA), c1b,
                                    (float*)(ws + WS_CSTATE), out, t);
  }
}

// Round 3
// 1507.476 us; speedup vs baseline: 1.1092x; 1.1092x over previous
//
#include <hip/hip_runtime.h>

typedef unsigned short u16;
typedef unsigned int   u32;
typedef __attribute__((ext_vector_type(8))) short short8;
typedef __attribute__((ext_vector_type(4))) float f32x4;

#define IMG_BYTES  557568      /* 66*66*64*2 (padded bf16 image) */
#define WS_SCALE   0
#define WS_SHIFT   256
#define WS_PART    512         /* 16 groups * 128 floats = 8192 B */
#define WS_WA      8704        /* 3 * 110592 u16 = 663552 B */
#define WS_BNXP    672256      /* 64 * IMG_BYTES */
#define WS_HC      (WS_BNXP + 64*IMG_BYTES)          /* 4 buffers x 4*IMG_BYTES */
#define WS_CSTATE  (WS_HC + 16*IMG_BYTES)            /* 4*64*4096 f32 = 4 MiB */

__device__ __forceinline__ u16 f2b(float f){
  u32 x = __float_as_uint(f);
  return (u16)((x + 0x7fffu + ((x>>16)&1u)) >> 16);
}
__device__ __forceinline__ float sigm(float x){ return 1.f/(1.f+__expf(-x)); }
__device__ __forceinline__ float tanh_(float x){
  float e = __expf(2.f*fabsf(x));
  float t = 1.f - 2.f/(e+1.f);      /* inf-safe -> 1 */
  return copysignf(t, x);
}

/* ---- weight transform: f32 [O][C][3][3] -> bf16 wA[j][o][tap*64+c] ---- */
__global__ void k_wt(const float* __restrict__ c1, const float* __restrict__ c2h,
                     const float* __restrict__ h2h, u16* __restrict__ wA){
  int idx = blockIdx.x*256 + threadIdx.x;
  if (idx >= 3*110592) return;
  int jj = idx / 110592, rem = idx % 110592;
  int o = rem / 576, k = rem % 576;
  int tap = k >> 6, c = k & 63;
  const float* src = (jj==0) ? c1 : ((jj==1) ? c2h : h2h);
  wA[idx] = f2b(src[(o*64 + c)*9 + tap]);
}

/* ---- BN partial sums: block (c, g) reduces imgs g*4..g*4+3 (f32 input) ---- */
__global__ void k_bnsum(const float* __restrict__ x, float* __restrict__ part){
  int c = blockIdx.x & 63, g = blockIdx.x >> 6;
  int tid = threadIdx.x, w = tid >> 6, lane = tid & 63;
  float s = 0.f, s2 = 0.f;
  for (int im = 0; im < 4; ++im){
    const float* base = x + (((size_t)((g*4+im)*64 + c)) << 12);
    #pragma unroll
    for (int it = 0; it < 4; ++it){
      float4 v = *(const float4*)(base + (((it<<8) + tid) << 2));
      s  += v.x + v.y + v.z + v.w;
      s2 += v.x*v.x + v.y*v.y + v.z*v.z + v.w*v.w;
    }
  }
  #pragma unroll
  for (int off = 32; off > 0; off >>= 1){
    s  += __shfl_down(s,  off);
    s2 += __shfl_down(s2, off);
  }
  __shared__ float red[8];
  if (lane == 0){ red[w] = s; red[4+w] = s2; }
  __syncthreads();
  if (tid == 0){
    float S  = red[0]+red[1]+red[2]+red[3];
    float S2 = red[4]+red[5]+red[6]+red[7];
    part[(g<<7) + c] = S;
    part[(g<<7) + 64 + c] = S2;
  }
}

/* ---- BN finalize: scale/shift per channel (f32 gamma/beta) ---- */
__global__ void k_bnfin(const float* __restrict__ part, const float* __restrict__ gamma,
                        const float* __restrict__ beta, float* __restrict__ scale,
                        float* __restrict__ shift){
  int c = threadIdx.x;
  float S = 0.f, S2 = 0.f;
  for (int g = 0; g < 16; ++g){ S += part[(g<<7)+c]; S2 += part[(g<<7)+64+c]; }
  const float inv = 1.f/262144.f;
  float mean = S*inv;
  float var  = S2*inv - mean*mean;
  float sc = gamma[c] * rsqrtf(var + 1e-5f);
  scale[c] = sc;
  shift[c] = beta[c] - mean*sc;
}

/* ---- BN apply + transpose f32 NCHW -> padded bf16 [img][66][66][64] ---- */
__global__ void k_bnx(const float* __restrict__ x, const float* __restrict__ scale,
                      const float* __restrict__ shift, char* __restrict__ bnxp){
  int img = blockIdx.x >> 6, r = blockIdx.x & 63;
  int col = threadIdx.x & 63, cq = threadIdx.x >> 6;
  const float* xb = x + (((size_t)(img*64 + cq*16)) << 12) + (r<<6) + col;
  union { u16 u[16]; uint4 v[2]; } pk;
  #pragma unroll
  for (int i = 0; i < 16; ++i){
    int c = cq*16 + i;
    float vv = xb[((size_t)i) << 12];
    pk.u[i] = f2b(vv*scale[c] + shift[c]);
  }
  char* dst = bnxp + (size_t)img*IMG_BYTES + ((size_t)((r+1)*66 + col + 1) << 7) + cq*32;
  *(uint4*)dst = pk.v[0];
  *(uint4*)(dst+16) = pk.v[1];
}

/* ---- fused ConvLSTM step: 256 blocks (1 image-row), 2 waves x 32 pos x 192 och ---- */
__global__ __launch_bounds__(128) void k_step(
    const char* __restrict__ bnxp,
    const char* __restrict__ cpad_s, const char* __restrict__ hpad_s,
    char* __restrict__ cpad_d, char* __restrict__ hpad_d,
    const u16* __restrict__ wA, const float* __restrict__ b1,
    float* __restrict__ cstate, float* __restrict__ out, int t)
{
  __shared__ __align__(16) char smem[28512];   /* 3 rows * 66 pos * 144 B */
  const int tid = threadIdx.x;
  const int w = tid >> 6, lane = tid & 63;
  const int l15 = lane & 15, l4 = lane >> 4;
  const int n = blockIdx.x >> 6, row = blockIdx.x & 63;
  const int colw = w << 5;

  const char* gb0 = bnxp  + (size_t)(t*4+n)*IMG_BYTES + row*8448;
  const char* gb1 = cpad_s + (size_t)n*IMG_BYTES + row*8448;
  const char* gb2 = hpad_s + (size_t)n*IMG_BYTES + row*8448;

  f32x4 acc[12][2];
  #pragma unroll
  for (int a = 0; a < 12; ++a){
    #pragma unroll
    for (int b = 0; b < 2; ++b)
      acc[a][b] = (f32x4){0.f,0.f,0.f,0.f};
  }

  const int boff = (colw + l15)*144 + l4*16;
  const int aoff = l15*1152 + l4*16;

  for (int j = 0; j < 3; ++j){
    const char* gbj = (j==0) ? gb0 : ((j==1) ? gb1 : gb2);
    if (j) __syncthreads();
    #pragma unroll
    for (int rr = 0; rr < 3; ++rr){
      const char* srcr = gbj + rr*8448;
      char* dstr = smem + rr*9504;
      for (int i = tid; i < 528; i += 128)
        *(uint4*)(dstr + (i>>3)*144 + ((i&7)<<4)) = *(const uint4*)(srcr + (i<<4));
    }
    __syncthreads();

    const char* wj = (const char*)wA + j*221184;
    for (int kh = 0; kh < 3; ++kh){
      #pragma unroll
      for (int kw = 0; kw < 3; ++kw){
        #pragma unroll
        for (int cc = 0; cc < 2; ++cc){
          const char* bp = smem + kh*9504 + kw*144 + boff + (cc<<6);
          short8 bf0 = *(const short8*)bp;
          short8 bf1 = *(const short8*)(bp + 2304);
          const char* wp = wj + aoff + (kh*3+kw)*128 + (cc<<6);
          #pragma unroll
          for (int fr = 0; fr < 12; ++fr){
            short8 af = *(const short8*)(wp + fr*18432);
            acc[fr][0] = __builtin_amdgcn_mfma_f32_16x16x32_bf16(af, bf0, acc[fr][0], 0,0,0);
            acc[fr][1] = __builtin_amdgcn_mfma_f32_16x16x32_bf16(af, bf1, acc[fr][1], 0,0,0);
          }
        }
      }
    }
  }

  /* epilogue: gates in-register; direct global stores (no barrier needed) */
  const size_t cb = ((size_t)(n*64)) << 12;
  const size_t ob = ((size_t)((t*4+n)*64)) << 12;
  const int prow = row << 6;
  char* hrow = hpad_d + (size_t)n*IMG_BYTES + (size_t)(row+1)*8448;
  char* crow = cpad_d + (size_t)n*IMG_BYTES + (size_t)(row+1)*8448;

  #pragma unroll
  for (int fr = 0; fr < 4; ++fr){
    const int gc0 = fr*16 + l4*4;
    #pragma unroll
    for (int cf = 0; cf < 2; ++cf){
      const int col = colw + (cf<<4) + l15;
      const int p = prow + col;
      union { u16 u[4]; uint2 v; } hp, cq4;
      #pragma unroll
      for (int r = 0; r < 4; ++r){
        const int gc = gc0 + r;
        float fv = acc[fr][cf][r]   + b1[gc];
        float ov = acc[fr+4][cf][r] + b1[64+gc];
        float gv = acc[fr+8][cf][r] + b1[128+gc];
        float f  = sigm(fv);
        float og = sigm(ov);
        float g  = tanh_(gv);
        float* cptr = cstate + cb + (((size_t)gc)<<12) + p;
        float cprev = *cptr;
        float cn = f*cprev + (1.f-f)*g;
        float hn = og * tanh_(cn);
        *cptr = cn;
        out[ob + (((size_t)gc)<<12) + p] = hn;
        hp.u[r]  = f2b(hn);
        cq4.u[r] = f2b(cn);
      }
      *(uint2*)(hrow + (size_t)(col+1)*128 + gc0*2) = hp.v;
      *(uint2*)(crow + (size_t)(col+1)*128 + gc0*2) = cq4.v;
    }
  }
}

extern "C" void kernel_launch(void* const* d_in, const int* in_sizes, int n_in,
                              void* d_out, int out_size, void* d_ws, size_t ws_size,
                              hipStream_t stream)
{
  (void)in_sizes; (void)n_in; (void)out_size; (void)ws_size;
  const float* x     = (const float*)d_in[0];
  const float* gamma = (const float*)d_in[1];
  const float* beta  = (const float*)d_in[2];
  const float* c1w   = (const float*)d_in[3];
  const float* c1b   = (const float*)d_in[4];
  const float* wh2h  = (const float*)d_in[5];
  const float* wc2h  = (const float*)d_in[6];
  char* ws  = (char*)d_ws;
  float* out = (float*)d_out;

  char* hpad0 = ws + WS_HC;
  char* cpad0 = ws + WS_HC + (size_t)4*IMG_BYTES;
  char* hpad1 = ws + WS_HC + (size_t)8*IMG_BYTES;
  char* cpad1 = ws + WS_HC + (size_t)12*IMG_BYTES;

  /* zero padded buffers (halos) + h/c ping-pong + c state; every call (graph-safe) */
  hipMemsetAsync(ws + WS_BNXP, 0, (size_t)64*IMG_BYTES, stream);
  hipMemsetAsync(ws + WS_HC, 0, (size_t)16*IMG_BYTES, stream);
  hipMemsetAsync(ws + WS_CSTATE, 0, (size_t)4*64*4096*4, stream);

  k_wt<<<1296, 256, 0, stream>>>(c1w, wc2h, wh2h, (u16*)(ws + WS_WA));
  k_bnsum<<<1024, 256, 0, stream>>>(x, (float*)(ws + WS_PART));
  k_bnfin<<<1, 64, 0, stream>>>((const float*)(ws + WS_PART), gamma, beta,
                                (float*)(ws + WS_SCALE), (float*)(ws + WS_SHIFT));
  k_bnx<<<4096, 256, 0, stream>>>(x, (const float*)(ws + WS_SCALE),
                                  (const float*)(ws + WS_SHIFT), ws + WS_BNXP);
  for (int t = 0; t < 16; ++t){
    const char* cs = (t & 1) ? cpad1 : cpad0;
    const char* hs = (t & 1) ? hpad1 : hpad0;
    char* cd = (t & 1) ? cpad0 : cpad1;
    char* hd = (t & 1) ? hpad0 : hpad1;
    k_step<<<256, 128, 0, stream>>>(ws + WS_BNXP, cs, hs, cd, hd,
                                    (const u16*)(ws + WS_WA), c1b,
                                    (float*)(ws + WS_CSTATE), out, t);
  }
}

// Round 4
// 548.882 us; speedup vs baseline: 3.0464x; 2.7464x over previous
//
#include <hip/hip_runtime.h>

typedef unsigned short u16;
typedef unsigned int   u32;
typedef __attribute__((ext_vector_type(8))) short short8;
typedef __attribute__((ext_vector_type(4))) float f32x4;

#define IMG_BYTES  557568      /* 66*66*64*2 (padded bf16 image) */
#define WS_SCALE   0
#define WS_SHIFT   256
#define WS_PART    512         /* 16 groups * 128 floats = 8192 B */
#define WS_WA      8704        /* 3 * 110592 u16 = 663552 B */
#define WS_BNXP    672256      /* 64 * IMG_BYTES */
#define WS_HC      (WS_BNXP + 64*IMG_BYTES)          /* 4 buffers x 4*IMG_BYTES */
#define WS_CSTATE  (WS_HC + 16*IMG_BYTES)            /* 4*64*4096 f32 = 4 MiB */

__device__ __forceinline__ u16 f2b(float f){
  u32 x = __float_as_uint(f);
  return (u16)((x + 0x7fffu + ((x>>16)&1u)) >> 16);
}
__device__ __forceinline__ float sigm(float x){ return 1.f/(1.f+__expf(-x)); }
__device__ __forceinline__ float tanh_(float x){
  float e = __expf(2.f*fabsf(x));
  float t = 1.f - 2.f/(e+1.f);      /* inf-safe -> 1 */
  return copysignf(t, x);
}

/* ---- weight transform: f32 [O][C][3][3] -> coalesced bf16 blocks ----
   dst u16 idx = (((j*9+tap)*2+cc)*12 + frg)*512 + lane*8 + e
   element = w_j[och = frg*16 + (lane&15)][c = cc*32 + (lane>>4)*8 + e] at tap */
__global__ void k_wt(const float* __restrict__ c1, const float* __restrict__ c2h,
                     const float* __restrict__ h2h, u16* __restrict__ wA){
  int idx = blockIdx.x*256 + threadIdx.x;   /* 1296*256 = 331776 exact */
  int e = idx & 7;
  int lane = (idx >> 3) & 63;
  int rest = idx >> 9;
  int frg = rest % 12;  rest /= 12;
  int cc = rest & 1;    rest >>= 1;
  int tap = rest % 9;
  int j = rest / 9;
  int och = frg*16 + (lane & 15);
  int c = cc*32 + (lane >> 4)*8 + e;
  const float* src = (j==0) ? c1 : ((j==1) ? c2h : h2h);
  wA[idx] = f2b(src[(och*64 + c)*9 + tap]);
}

/* ---- BN partial sums: block (c, g) reduces imgs g*4..g*4+3 (f32 input) ---- */
__global__ void k_bnsum(const float* __restrict__ x, float* __restrict__ part){
  int c = blockIdx.x & 63, g = blockIdx.x >> 6;
  int tid = threadIdx.x, w = tid >> 6, lane = tid & 63;
  float s = 0.f, s2 = 0.f;
  for (int im = 0; im < 4; ++im){
    const float* base = x + (((size_t)((g*4+im)*64 + c)) << 12);
    #pragma unroll
    for (int it = 0; it < 4; ++it){
      float4 v = *(const float4*)(base + (((it<<8) + tid) << 2));
      s  += v.x + v.y + v.z + v.w;
      s2 += v.x*v.x + v.y*v.y + v.z*v.z + v.w*v.w;
    }
  }
  #pragma unroll
  for (int off = 32; off > 0; off >>= 1){
    s  += __shfl_down(s,  off);
    s2 += __shfl_down(s2, off);
  }
  __shared__ float red[8];
  if (lane == 0){ red[w] = s; red[4+w] = s2; }
  __syncthreads();
  if (tid == 0){
    float S  = red[0]+red[1]+red[2]+red[3];
    float S2 = red[4]+red[5]+red[6]+red[7];
    part[(g<<7) + c] = S;
    part[(g<<7) + 64 + c] = S2;
  }
}

/* ---- BN finalize: scale/shift per channel (f32 gamma/beta) ---- */
__global__ void k_bnfin(const float* __restrict__ part, const float* __restrict__ gamma,
                        const float* __restrict__ beta, float* __restrict__ scale,
                        float* __restrict__ shift){
  int c = threadIdx.x;
  float S = 0.f, S2 = 0.f;
  for (int g = 0; g < 16; ++g){ S += part[(g<<7)+c]; S2 += part[(g<<7)+64+c]; }
  const float inv = 1.f/262144.f;
  float mean = S*inv;
  float var  = S2*inv - mean*mean;
  float sc = gamma[c] * rsqrtf(var + 1e-5f);
  scale[c] = sc;
  shift[c] = beta[c] - mean*sc;
}

/* ---- BN apply + transpose f32 NCHW -> padded bf16 [img][66][66][64] ---- */
__global__ void k_bnx(const float* __restrict__ x, const float* __restrict__ scale,
                      const float* __restrict__ shift, char* __restrict__ bnxp){
  int img = blockIdx.x >> 6, r = blockIdx.x & 63;
  int col = threadIdx.x & 63, cq = threadIdx.x >> 6;
  const float* xb = x + (((size_t)(img*64 + cq*16)) << 12) + (r<<6) + col;
  union { u16 u[16]; uint4 v[2]; } pk;
  #pragma unroll
  for (int i = 0; i < 16; ++i){
    int c = cq*16 + i;
    float vv = xb[((size_t)i) << 12];
    pk.u[i] = f2b(vv*scale[c] + shift[c]);
  }
  char* dst = bnxp + (size_t)img*IMG_BYTES + ((size_t)((r+1)*66 + col + 1) << 7) + cq*32;
  *(uint4*)dst = pk.v[0];
  *(uint4*)(dst+16) = pk.v[1];
}

/* ---- fused ConvLSTM step: 256 blocks (1 row each), 4 waves:
        wave q computes och-quarter {f,o,g} x all 64 positions ---- */
__global__ __launch_bounds__(256, 1) void k_step(
    const char* __restrict__ bnxp,
    const char* __restrict__ cpad_s, const char* __restrict__ hpad_s,
    char* __restrict__ cpad_d, char* __restrict__ hpad_d,
    const char* __restrict__ wA, const float* __restrict__ b1,
    float* __restrict__ cstate, float* __restrict__ out, int t)
{
  __shared__ __align__(16) char smem[28512];   /* 3 rows * 66 pos * 144 B */
  const int tid = threadIdx.x;
  const int q = tid >> 6, lane = tid & 63;
  const int l15 = lane & 15, l4 = lane >> 4;
  const int n = blockIdx.x >> 6, row = blockIdx.x & 63;

  const char* gb0 = bnxp  + (size_t)(t*4+n)*IMG_BYTES + row*8448;
  const char* gb1 = cpad_s + (size_t)n*IMG_BYTES + row*8448;
  const char* gb2 = hpad_s + (size_t)n*IMG_BYTES + row*8448;

  f32x4 acc[3][4];
  #pragma unroll
  for (int a = 0; a < 3; ++a)
    #pragma unroll
    for (int b = 0; b < 4; ++b)
      acc[a][b] = (f32x4){0.f,0.f,0.f,0.f};

  for (int j = 0; j < 3; ++j){
    const char* gbj = (j==0) ? gb0 : ((j==1) ? gb1 : gb2);
    if (j) __syncthreads();
    for (int i = tid; i < 1584; i += 256){
      int rr = i / 528, iw = i % 528;
      *(uint4*)(smem + rr*9504 + (iw>>3)*144 + ((iw&7)<<4)) =
          *(const uint4*)(gbj + rr*8448 + (i%528 << 4));
    }
    __syncthreads();

    const char* wj = wA + j*221184 + q*1024 + lane*16;
    #pragma unroll
    for (int kh = 0; kh < 3; ++kh){
      #pragma unroll
      for (int kw = 0; kw < 3; ++kw){
        #pragma unroll
        for (int cc = 0; cc < 2; ++cc){
          const char* ab = wj + ((kh*3+kw)*2 + cc)*12288;
          short8 a0 = *(const short8*)(ab);
          short8 a1 = *(const short8*)(ab + 4096);
          short8 a2 = *(const short8*)(ab + 8192);
          const char* bb = smem + kh*9504 + (kw + l15)*144 + l4*16 + (cc<<6);
          #pragma unroll
          for (int cf = 0; cf < 4; ++cf){
            short8 bf = *(const short8*)(bb + cf*2304);
            acc[0][cf] = __builtin_amdgcn_mfma_f32_16x16x32_bf16(a0, bf, acc[0][cf], 0,0,0);
            acc[1][cf] = __builtin_amdgcn_mfma_f32_16x16x32_bf16(a1, bf, acc[1][cf], 0,0,0);
            acc[2][cf] = __builtin_amdgcn_mfma_f32_16x16x32_bf16(a2, bf, acc[2][cf], 0,0,0);
          }
        }
      }
    }
  }

  /* epilogue: gates in-register; wave q owns och q*16..q*16+15, all 64 pos */
  const size_t cb = ((size_t)(n*64)) << 12;
  const size_t ob = ((size_t)((t*4+n)*64)) << 12;
  const int prow = row << 6;
  const int gc0 = q*16 + l4*4;
  char* hrow = hpad_d + (size_t)n*IMG_BYTES + (size_t)(row+1)*8448;
  char* crow = cpad_d + (size_t)n*IMG_BYTES + (size_t)(row+1)*8448;

  #pragma unroll
  for (int cf = 0; cf < 4; ++cf){
    const int col = cf*16 + l15;
    const int p = prow + col;
    union { u16 u[4]; uint2 v; } hp, cq4;
    #pragma unroll
    for (int r = 0; r < 4; ++r){
      const int gc = gc0 + r;
      float fv = acc[0][cf][r] + b1[gc];
      float ov = acc[1][cf][r] + b1[64+gc];
      float gv = acc[2][cf][r] + b1[128+gc];
      float f  = sigm(fv);
      float og = sigm(ov);
      float g  = tanh_(gv);
      float* cptr = cstate + cb + (((size_t)gc)<<12) + p;
      float cprev = *cptr;
      float cn = f*cprev + (1.f-f)*g;
      float hn = og * tanh_(cn);
      *cptr = cn;
      out[ob + (((size_t)gc)<<12) + p] = hn;
      hp.u[r]  = f2b(hn);
      cq4.u[r] = f2b(cn);
    }
    *(uint2*)(hrow + (size_t)(col+1)*128 + gc0*2) = hp.v;
    *(uint2*)(crow + (size_t)(col+1)*128 + gc0*2) = cq4.v;
  }
}

extern "C" void kernel_launch(void* const* d_in, const int* in_sizes, int n_in,
                              void* d_out, int out_size, void* d_ws, size_t ws_size,
                              hipStream_t stream)
{
  (void)in_sizes; (void)n_in; (void)out_size; (void)ws_size;
  const float* x     = (const float*)d_in[0];
  const float* gamma = (const float*)d_in[1];
  const float* beta  = (const float*)d_in[2];
  const float* c1w   = (const float*)d_in[3];
  const float* c1b   = (const float*)d_in[4];
  const float* wh2h  = (const float*)d_in[5];
  const float* wc2h  = (const float*)d_in[6];
  char* ws  = (char*)d_ws;
  float* out = (float*)d_out;

  char* hpad0 = ws + WS_HC;
  char* cpad0 = ws + WS_HC + (size_t)4*IMG_BYTES;
  char* hpad1 = ws + WS_HC + (size_t)8*IMG_BYTES;
  char* cpad1 = ws + WS_HC + (size_t)12*IMG_BYTES;

  /* zero padded buffers (halos) + h/c ping-pong + c state; every call (graph-safe) */
  hipMemsetAsync(ws + WS_BNXP, 0, (size_t)64*IMG_BYTES, stream);
  hipMemsetAsync(ws + WS_HC, 0, (size_t)16*IMG_BYTES, stream);
  hipMemsetAsync(ws + WS_CSTATE, 0, (size_t)4*64*4096*4, stream);

  k_wt<<<1296, 256, 0, stream>>>(c1w, wc2h, wh2h, (u16*)(ws + WS_WA));
  k_bnsum<<<1024, 256, 0, stream>>>(x, (float*)(ws + WS_PART));
  k_bnfin<<<1, 64, 0, stream>>>((const float*)(ws + WS_PART), gamma, beta,
                                (float*)(ws + WS_SCALE), (float*)(ws + WS_SHIFT));
  k_bnx<<<4096, 256, 0, stream>>>(x, (const float*)(ws + WS_SCALE),
                                  (const float*)(ws + WS_SHIFT), ws + WS_BNXP);
  for (int t = 0; t < 16; ++t){
    const char* cs = (t & 1) ? cpad1 : cpad0;
    const char* hs = (t & 1) ? hpad1 : hpad0;
    char* cd = (t & 1) ? cpad0 : cpad1;
    char* hd = (t & 1) ? hpad0 : hpad1;
    k_step<<<256, 256, 0, stream>>>(ws + WS_BNXP, cs, hs, cd, hd,
                                    ws + WS_WA, c1b,
                                    (float*)(ws + WS_CSTATE), out, t);
  }
}